// Round 9
// baseline (546.495 us; speedup 1.0000x reference)
//
#include <hip/hip_runtime.h>

// ---------------------------------------------------------------------------
// ImageTextModule: dual cross-attention between text and image feature sets.
//   t = text @ w_text^T + b_text ; i = image @ w_image^T + b_image  (bf16)
//   P  = exp((t @ i^T) / 32)  materialized ONCE in bf16, BOTH layouts (P, PT);
//        row/col exp-sums fused (wave-pair LDS pre-combine -> 1 atomic per
//        row/col per block — halves atomics, kills same-address collisions).
//   out0 = (scale_TI / lT) * P  @ image ; out1 = (scale_IT / lI) * PT @ text
// attn: 512-thr, in-block split-K=2, 2x unroll, symmetric 2-sync LDS merge
//       with the epilogue split across all 8 waves.
// proj: 128x64 tiles -> 1024 blocks = 4/CU, 32 waves/CU (was grid-starved
//       at 512 blocks; split-K loses at K=1024 per round-7).
// K-loops: m97 structure — unpadded [rows][32] LDS, global_load_lds width-16,
// bf16 MFMA 16x16x32, fp32 accumulate.  Workspace: 96 MB + 32 KB.
// ---------------------------------------------------------------------------

typedef __bf16 bf16x8 __attribute__((ext_vector_type(8)));
typedef float f32x4 __attribute__((ext_vector_type(4)));

#define N_T 4096
#define N_I 4096
#define DIM 1024
#define TSS 136  // epilogue tile stride (bf16): 128 + 8 pad

__device__ __forceinline__ unsigned short f2bf(float f) {
    unsigned int u = __float_as_uint(f);
    u += 0x7fffu + ((u >> 16) & 1u);  // RNE
    return (unsigned short)(u >> 16);
}

// 16-byte async global->LDS DMA (no VGPR round-trip).
__device__ __forceinline__ void async_cp16(const unsigned short* g, unsigned short* l) {
    __builtin_amdgcn_global_load_lds(
        (const __attribute__((address_space(1))) unsigned int*)g,
        (__attribute__((address_space(3))) unsigned int*)l, 16, 0, 0);
}

// Stage 128x32 bf16 tile -> unpadded LDS [128][32] with 256 threads.
__device__ __forceinline__ void stage_async(const unsigned short* __restrict__ src,
                                            int ld, int row0, int k0,
                                            unsigned short* lds, int t) {
    int r = t >> 2, c = (t & 3) << 3;
    const unsigned short* g = src + (size_t)(row0 + r) * ld + k0 + c;
    async_cp16(g, lds + r * 32 + c);
    async_cp16(g + (size_t)64 * ld, lds + (64 + r) * 32 + c);
}

// Stage 64x32 bf16 tile -> unpadded LDS [64][32] with 256 threads (1 cp16 ea).
__device__ __forceinline__ void stage_async64(const unsigned short* __restrict__ src,
                                              int ld, int row0, int k0,
                                              unsigned short* lds, int t) {
    int r = t >> 2, c = (t & 3) << 3;
    async_cp16(src + (size_t)(row0 + r) * ld + k0 + c, lds + r * 32 + c);
}

// One BK=32 MFMA step, 4x4 frags (64x64 wave tile).
__device__ __forceinline__ void mfma_step(const unsigned short* As,
                                          const unsigned short* Bs, f32x4 acc[4][4],
                                          int wrow, int wcol, int lane16, int quad) {
    bf16x8 a[4], b[4];
#pragma unroll
    for (int i = 0; i < 4; ++i) {
        a[i] = *(const bf16x8*)&As[(wrow + i * 16 + lane16) * 32 + quad * 8];
        b[i] = *(const bf16x8*)&Bs[(wcol + i * 16 + lane16) * 32 + quad * 8];
    }
#pragma unroll
    for (int i = 0; i < 4; ++i)
#pragma unroll
        for (int j = 0; j < 4; ++j)
            acc[i][j] = __builtin_amdgcn_mfma_f32_16x16x32_bf16(a[i], b[j], acc[i][j], 0, 0, 0);
}

// One BK=32 MFMA step, 4x2 frags (64x32 wave tile) — proj's 128x64 tiling.
__device__ __forceinline__ void mfma_step42(const unsigned short* As,
                                            const unsigned short* Bs, f32x4 acc[4][2],
                                            int wrow, int wcol, int lane16, int quad) {
    bf16x8 a[4], b[2];
#pragma unroll
    for (int i = 0; i < 4; ++i)
        a[i] = *(const bf16x8*)&As[(wrow + i * 16 + lane16) * 32 + quad * 8];
#pragma unroll
    for (int j = 0; j < 2; ++j)
        b[j] = *(const bf16x8*)&Bs[(wcol + j * 16 + lane16) * 32 + quad * 8];
#pragma unroll
    for (int i = 0; i < 4; ++i)
#pragma unroll
        for (int j = 0; j < 2; ++j)
            acc[i][j] = __builtin_amdgcn_mfma_f32_16x16x32_bf16(a[i], b[j], acc[i][j], 0, 0, 0);
}

// Coalesced 128x128 bf16 tile store from LDS (stride TSS) to global.
__device__ __forceinline__ void tile_store(const unsigned short* sm,
                                           unsigned short* __restrict__ g, int ld,
                                           int row0, int col0, int tid) {
    int r = tid >> 1, h = (tid & 1) << 6;
    const unsigned short* src = sm + r * TSS + h;
    unsigned short* dst = g + (size_t)(row0 + r) * ld + col0 + h;
#pragma unroll
    for (int v = 0; v < 8; ++v)
        *(uint4*)(dst + v * 8) = *(const uint4*)(src + v * 8);
}

// ---- unified pre-pass ------------------------------------------------------
// z=0: image 64x64 tile -> image_bf + imgT      z=1: text -> text_bf + textT
// z=2: weights flat cvt (lin id over 1024 blocks); blocks 0-3 zero lT/lI.
__global__ void __launch_bounds__(256)
cvt_all(const float* __restrict__ im, const float* __restrict__ tx,
        const float* __restrict__ wt, const float* __restrict__ wi,
        unsigned short* __restrict__ imb, unsigned short* __restrict__ txb,
        unsigned short* __restrict__ imgT, unsigned short* __restrict__ textT,
        unsigned short* __restrict__ wtb, unsigned short* __restrict__ wib,
        float* __restrict__ lTI) {
    int t = threadIdx.x;
    if (blockIdx.z == 2) {
        int lin = blockIdx.y * 64 + blockIdx.x;  // 0..1023
        if (lin < 4) {
            *(f32x4*)&lTI[(lin * 256 + t) * 8] = (f32x4){0.f, 0.f, 0.f, 0.f};
            *(f32x4*)&lTI[(lin * 256 + t) * 8 + 4] = (f32x4){0.f, 0.f, 0.f, 0.f};
        }
        size_t i = (size_t)(lin * 256 + t) * 8;
        const float* s;
        unsigned short* d;
        size_t off;
        if (i < 1048576) { s = wt; d = wtb; off = i; }
        else             { s = wi; d = wib; off = i - 1048576; }
        float4 f0 = *(const float4*)(s + off);
        float4 f1 = *(const float4*)(s + off + 4);
        uint4 o;
        o.x = (unsigned int)f2bf(f0.x) | ((unsigned int)f2bf(f0.y) << 16);
        o.y = (unsigned int)f2bf(f0.z) | ((unsigned int)f2bf(f0.w) << 16);
        o.z = (unsigned int)f2bf(f1.x) | ((unsigned int)f2bf(f1.y) << 16);
        o.w = (unsigned int)f2bf(f1.z) | ((unsigned int)f2bf(f1.w) << 16);
        *(uint4*)(d + off) = o;
        return;
    }
    const float* in = blockIdx.z ? tx : im;
    unsigned short* nb = blockIdx.z ? txb : imb;
    unsigned short* tr = blockIdx.z ? textT : imgT;
    __shared__ float tile[64][65];
    int row0 = blockIdx.x * 64, col0 = blockIdx.y * 64;
    int r = t >> 2, c = (t & 3) << 4;  // 64 rows x 4 col-chunks of 16
    {
        const float* p = in + (size_t)(row0 + r) * DIM + col0 + c;
        float4 f0 = *(const float4*)(p);
        float4 f1 = *(const float4*)(p + 4);
        float4 f2 = *(const float4*)(p + 8);
        float4 f3 = *(const float4*)(p + 12);
        *(float4*)&tile[r][c] = f0;
        *(float4*)&tile[r][c + 4] = f1;
        *(float4*)&tile[r][c + 8] = f2;
        *(float4*)&tile[r][c + 12] = f3;
        uint4 o0, o1;
        o0.x = (unsigned int)f2bf(f0.x) | ((unsigned int)f2bf(f0.y) << 16);
        o0.y = (unsigned int)f2bf(f0.z) | ((unsigned int)f2bf(f0.w) << 16);
        o0.z = (unsigned int)f2bf(f1.x) | ((unsigned int)f2bf(f1.y) << 16);
        o0.w = (unsigned int)f2bf(f1.z) | ((unsigned int)f2bf(f1.w) << 16);
        o1.x = (unsigned int)f2bf(f2.x) | ((unsigned int)f2bf(f2.y) << 16);
        o1.y = (unsigned int)f2bf(f2.z) | ((unsigned int)f2bf(f2.w) << 16);
        o1.z = (unsigned int)f2bf(f3.x) | ((unsigned int)f2bf(f3.y) << 16);
        o1.w = (unsigned int)f2bf(f3.z) | ((unsigned int)f2bf(f3.w) << 16);
        unsigned short* q = nb + (size_t)(row0 + r) * DIM + col0 + c;
        *(uint4*)q = o0;
        *(uint4*)(q + 8) = o1;
    }
    __syncthreads();
    {
        unsigned short v[16];
#pragma unroll
        for (int u = 0; u < 16; ++u) v[u] = f2bf(tile[c + u][r]);
        unsigned short* q = tr + (size_t)(col0 + r) * N_T + row0 + c;
        *(uint4*)q = *(uint4*)&v[0];
        *(uint4*)(q + 8) = *(uint4*)&v[8];
    }
}

// ---- fused projections: 128x64 tiles, 1024 blocks = 4/CU, 32 waves/CU ------
// C_bf16[4096][1024] = A_bf16 @ W_bf16^T + bias.  z: text / image.
__global__ void __launch_bounds__(256, 4)
gemm_proj2(const unsigned short* __restrict__ Atx, const unsigned short* __restrict__ Wtx,
           const float* __restrict__ btx, unsigned short* __restrict__ Ctx,
           const unsigned short* __restrict__ Aim, const unsigned short* __restrict__ Wim,
           const float* __restrict__ bim, unsigned short* __restrict__ Cim) {
    __shared__ unsigned short As[2][128 * 32];  // 16 KB
    __shared__ unsigned short Bs[2][64 * 32];   // 8 KB
    int z = blockIdx.z;
    const unsigned short* A = z ? Aim : Atx;
    const unsigned short* W = z ? Wim : Wtx;
    const float* bias = z ? bim : btx;
    unsigned short* C = z ? Cim : Ctx;
    int tid = threadIdx.x;
    int m0 = blockIdx.x * 128, n0 = blockIdx.y * 64;
    int lane = tid & 63, wave = tid >> 6;
    int lane16 = lane & 15, quad = lane >> 4;
    int wrow = (wave >> 1) * 64, wcol = (wave & 1) * 32;
    f32x4 acc[4][2];
    {
        f32x4 zz = {0.f, 0.f, 0.f, 0.f};
        for (int i = 0; i < 4; ++i)
            for (int j = 0; j < 2; ++j) acc[i][j] = zz;
    }
    for (int k0 = 0; k0 < DIM; k0 += 64) {
        stage_async(A, DIM, m0, k0, As[0], tid);
        stage_async64(W, DIM, n0, k0, Bs[0], tid);
        stage_async(A, DIM, m0, k0 + 32, As[1], tid);
        stage_async64(W, DIM, n0, k0 + 32, Bs[1], tid);
        __syncthreads();
        mfma_step42(As[0], Bs[0], acc, wrow, wcol, lane16, quad);
        mfma_step42(As[1], Bs[1], acc, wrow, wcol, lane16, quad);
        __syncthreads();
    }
#pragma unroll
    for (int j = 0; j < 2; ++j) {
        int col = n0 + wcol + j * 16 + lane16;
        float bv = bias[col];
#pragma unroll
        for (int i = 0; i < 4; ++i) {
            int rowb = m0 + wrow + i * 16 + quad * 4;
#pragma unroll
            for (int r = 0; r < 4; ++r)
                C[(size_t)(rowb + r) * DIM + col] = f2bf(acc[i][j][r] + bv);
        }
    }
}

// ---- logits+exp: P/PT bf16 (both layouts) + fused row/col exp-sums ---------
// Wave-pair LDS pre-combine -> one atomic per row/col per block.
__global__ void __launch_bounds__(256, 4)
gemm_logits_exp(const unsigned short* __restrict__ Tb,
                const unsigned short* __restrict__ Ib,
                unsigned short* __restrict__ P, unsigned short* __restrict__ PT,
                float* __restrict__ lT, float* __restrict__ lI) {
    __shared__ unsigned short smem[128 * TSS];  // 34.8 KB: K-bufs + epilogue
    unsigned short* As0 = smem;
    unsigned short* Bs0 = smem + 4096;
    unsigned short* As1 = smem + 8192;
    unsigned short* Bs1 = smem + 12288;
    float* lred = (float*)(smem + 16384);  // 128 floats (free tail of smem)
    float* cred = lred + 128;              // 128 floats
    int tid = threadIdx.x;
    int m0 = blockIdx.x * 128, n0 = blockIdx.y * 128;
    int lane = tid & 63, wave = tid >> 6;
    int lane16 = lane & 15, quad = lane >> 4;
    int wrow = (wave >> 1) * 64, wcol = (wave & 1) * 64;
    f32x4 acc[4][4];
    {
        f32x4 z = {0.f, 0.f, 0.f, 0.f};
        for (int i = 0; i < 4; ++i)
            for (int j = 0; j < 4; ++j) acc[i][j] = z;
    }
    for (int k0 = 0; k0 < DIM; k0 += 64) {
        stage_async(Tb, DIM, m0, k0, As0, tid);
        stage_async(Ib, DIM, n0, k0, Bs0, tid);
        stage_async(Tb, DIM, m0, k0 + 32, As1, tid);
        stage_async(Ib, DIM, n0, k0 + 32, Bs1, tid);
        __syncthreads();
        mfma_step(As0, Bs0, acc, wrow, wcol, lane16, quad);
        mfma_step(As1, Bs1, acc, wrow, wcol, lane16, quad);
        __syncthreads();
    }
    // p = exp(logit/32) in place (fp32)
#pragma unroll
    for (int i = 0; i < 4; ++i)
#pragma unroll
        for (int j = 0; j < 4; ++j)
#pragma unroll
            for (int r = 0; r < 4; ++r)
                acc[i][j][r] = __expf(acc[i][j][r] * 0.03125f);
    // wave partials: rows (this wave's 64 cols) and cols (this wave's 64 rows)
    float rs[4][4];  // row partial, valid at lane16==0
#pragma unroll
    for (int i = 0; i < 4; ++i)
#pragma unroll
        for (int r = 0; r < 4; ++r) {
            float s = acc[i][0][r] + acc[i][1][r] + acc[i][2][r] + acc[i][3][r];
            s += __shfl_xor(s, 1); s += __shfl_xor(s, 2);
            s += __shfl_xor(s, 4); s += __shfl_xor(s, 8);
            rs[i][r] = s;
        }
    float cs[4];  // col partial, valid at quad==0
#pragma unroll
    for (int j = 0; j < 4; ++j) {
        float s = 0.f;
#pragma unroll
        for (int i = 0; i < 4; ++i)
#pragma unroll
            for (int r = 0; r < 4; ++r) s += acc[i][j][r];
        s += __shfl_xor(s, 16); s += __shfl_xor(s, 32);
        cs[j] = s;
    }
    // donors: waves 1,3 stash row partials; waves 2,3 stash col partials
    if (wave & 1) {
        if (lane16 == 0)
#pragma unroll
            for (int i = 0; i < 4; ++i)
#pragma unroll
                for (int r = 0; r < 4; ++r)
                    lred[wrow + i * 16 + quad * 4 + r] = rs[i][r];
    }
    if (wave >> 1) {
        if (quad == 0)
#pragma unroll
            for (int j = 0; j < 4; ++j)
                cred[wcol + j * 16 + lane16] = cs[j];
    }
    __syncthreads();
    // combiners: waves 0,2 finish rows; waves 0,1 finish cols
    if (!(wave & 1) && lane16 == 0) {
#pragma unroll
        for (int i = 0; i < 4; ++i)
#pragma unroll
            for (int r = 0; r < 4; ++r) {
                int row = wrow + i * 16 + quad * 4 + r;
                atomicAdd(&lT[m0 + row], rs[i][r] + lred[row]);
            }
    }
    if (!(wave >> 1) && quad == 0) {
#pragma unroll
        for (int j = 0; j < 4; ++j) {
            int col = wcol + j * 16 + lane16;
            atomicAdd(&lI[n0 + col], cs[j] + cred[col]);
        }
    }
    // pass 1: normal-layout tile -> P (coalesced b128 stores)
    __syncthreads();
#pragma unroll
    for (int i = 0; i < 4; ++i)
#pragma unroll
        for (int j = 0; j < 4; ++j)
#pragma unroll
            for (int r = 0; r < 4; ++r)
                smem[(wrow + i * 16 + quad * 4 + r) * TSS + wcol + j * 16 + lane16] =
                    f2bf(acc[i][j][r]);
    __syncthreads();
    tile_store(smem, P, N_I, m0, n0, tid);
    // pass 2: transposed tile -> PT (b64 LDS writes, coalesced b128 stores)
    __syncthreads();
#pragma unroll
    for (int i = 0; i < 4; ++i)
#pragma unroll
        for (int j = 0; j < 4; ++j) {
            unsigned int lo = (unsigned int)f2bf(acc[i][j][0]) |
                              ((unsigned int)f2bf(acc[i][j][1]) << 16);
            unsigned int hi = (unsigned int)f2bf(acc[i][j][2]) |
                              ((unsigned int)f2bf(acc[i][j][3]) << 16);
            uint2 v; v.x = lo; v.y = hi;
            *(uint2*)&smem[(wcol + j * 16 + lane16) * TSS + wrow + i * 16 + quad * 4] = v;
        }
    __syncthreads();
    tile_store(smem, PT, N_T, n0, m0, tid);
}

// ---- fused attention GEMMs: 512 thr, split-K=2, 2x unroll, 2-sync merge ----
// z: which problem. out[m][d] = (scale/l[m]) * sum_k A[m][k] * Bt[d][k].
// Merge: half-1 donates i=0,1 (half-0 finishes+stores); half-0 donates i=2,3
// (half-1 finishes+stores) — all 8 waves store, 2 barriers total.
__global__ void __launch_bounds__(512, 4)
gemm_attn2(const unsigned short* __restrict__ P, const unsigned short* __restrict__ imgT,
           const float* __restrict__ lT, const float* __restrict__ sTI,
           float* __restrict__ out0,
           const unsigned short* __restrict__ PT, const unsigned short* __restrict__ textT,
           const float* __restrict__ lI, const float* __restrict__ sIT,
           float* __restrict__ out1) {
    __shared__ unsigned short As[2][2][128 * 32];  // [half][unroll] 32 KB
    __shared__ unsigned short Bs[2][2][128 * 32];  // 32 KB
    int which = blockIdx.z;
    const unsigned short* A = which ? PT : P;
    const unsigned short* Bt = which ? textT : imgT;
    const float* l = which ? lI : lT;
    const float* sp = which ? sIT : sTI;
    float* out = which ? out1 : out0;

    int tid = threadIdx.x;            // 0..511
    int half = tid >> 8;              // K-half (wave-uniform)
    int t = tid & 255;                // index within half-group
    int m0 = blockIdx.x * 128, n0 = blockIdx.y * 128;
    int lane = tid & 63;
    int wv = (tid >> 6) & 3;          // wave within half-group
    int lane16 = lane & 15, quad = lane >> 4;
    int wrow = (wv >> 1) * 64, wcol = (wv & 1) * 64;
    f32x4 acc[4][4];
    {
        f32x4 z = {0.f, 0.f, 0.f, 0.f};
        for (int i = 0; i < 4; ++i)
            for (int j = 0; j < 4; ++j) acc[i][j] = z;
    }

    int kbeg = half * 2048;
    for (int k0 = kbeg; k0 < kbeg + 2048; k0 += 64) {  // 32 lockstep iterations
        stage_async(A, 4096, m0, k0, As[half][0], t);
        stage_async(Bt, 4096, n0, k0, Bs[half][0], t);
        stage_async(A, 4096, m0, k0 + 32, As[half][1], t);
        stage_async(Bt, 4096, n0, k0 + 32, Bs[half][1], t);
        __syncthreads();
        mfma_step(As[half][0], Bs[half][0], acc, wrow, wcol, lane16, quad);
        mfma_step(As[half][1], Bs[half][1], acc, wrow, wcol, lane16, quad);
        __syncthreads();
    }

    // Symmetric 2-sync merge (reuse As as 32 KB scratch; stride-16 -> 2-way).
    float* red = (float*)As;
    if (half) {  // donate i=0,1
#pragma unroll
        for (int i = 0; i < 2; ++i)
#pragma unroll
            for (int j = 0; j < 4; ++j)
                *(f32x4*)&red[(wv * 2 + i) * 1024 + lane * 16 + j * 4] = acc[i][j];
    }
    __syncthreads();
    if (!half) {  // finish i=0,1; donate i=2,3
#pragma unroll
        for (int i = 0; i < 2; ++i)
#pragma unroll
            for (int j = 0; j < 4; ++j)
                acc[i][j] += *(const f32x4*)&red[(wv * 2 + i) * 1024 + lane * 16 + j * 4];
#pragma unroll
        for (int i = 2; i < 4; ++i)
#pragma unroll
            for (int j = 0; j < 4; ++j)
                *(f32x4*)&red[(wv * 2 + i - 2) * 1024 + lane * 16 + j * 4] = acc[i][j];
    }
    __syncthreads();
    if (half) {  // finish i=2,3
#pragma unroll
        for (int i = 2; i < 4; ++i)
#pragma unroll
            for (int j = 0; j < 4; ++j)
                acc[i][j] += *(const f32x4*)&red[(wv * 2 + i - 2) * 1024 + lane * 16 + j * 4];
    }

    // Epilogue split: half-0 stores i=0,1 ; half-1 stores i=2,3.
    float sc = sp[0];
    int ibeg = half ? 2 : 0;
#pragma unroll
    for (int i = 0; i < 2; ++i) {
        int ii = ibeg + i;
        int rowb = m0 + wrow + ii * 16 + quad * 4;
        float fac[4];
#pragma unroll
        for (int r = 0; r < 4; ++r) fac[r] = sc / l[rowb + r];
#pragma unroll
        for (int j = 0; j < 4; ++j) {
            int col = n0 + wcol + j * 16 + lane16;
#pragma unroll
            for (int r = 0; r < 4; ++r)
                out[(size_t)(rowb + r) * DIM + col] = acc[ii][j][r] * fac[r];
        }
    }
}

extern "C" void kernel_launch(void* const* d_in, const int* in_sizes, int n_in,
                              void* d_out, int out_size, void* d_ws, size_t ws_size,
                              hipStream_t stream) {
    const float* text = (const float*)d_in[0];
    const float* image = (const float*)d_in[1];
    const float* w_text = (const float*)d_in[2];
    const float* b_text = (const float*)d_in[3];
    const float* w_image = (const float*)d_in[4];
    const float* b_image = (const float*)d_in[5];
    const float* scale_TI = (const float*)d_in[6];
    const float* scale_IT = (const float*)d_in[7];
    float* out0 = (float*)d_out;
    float* out1 = out0 + (size_t)N_T * DIM;

    // Workspace layout (96 MB + 32 KB). cvt buffers [0,20MB) die after proj2;
    // gemm_logits_exp then writes P over [0,32MB) — lifetimes disjoint.
    char* ws = (char*)d_ws;
    unsigned short* text_bf = (unsigned short*)(ws);                 // 8 MB  (dies after proj)
    unsigned short* image_bf = (unsigned short*)(ws + (8ull << 20)); // 8 MB  (dies after proj)
    unsigned short* wt_bf = (unsigned short*)(ws + (16ull << 20));   // 2 MB  (dies after proj)
    unsigned short* wi_bf = (unsigned short*)(ws + (18ull << 20));   // 2 MB  (dies after proj)
    unsigned short* P = (unsigned short*)(ws);                       // 32 MB (logits -> attn)
    unsigned short* imgT = (unsigned short*)(ws + (32ull << 20));    // 8 MB
    unsigned short* textT = (unsigned short*)(ws + (40ull << 20));   // 8 MB
    unsigned short* t_bf = (unsigned short*)(ws + (48ull << 20));    // 8 MB
    unsigned short* i_bf = (unsigned short*)(ws + (56ull << 20));    // 8 MB
    unsigned short* PT = (unsigned short*)(ws + (64ull << 20));      // 32 MB
    float* lT = (float*)(ws + (96ull << 20));                        // 16 KB
    float* lI = (float*)(ws + (96ull << 20) + 16384);                // 16 KB

    // z=0/1: feature 64x64 cvt+transpose tiles; z=2: weights cvt + lT/lI zero.
    cvt_all<<<dim3(N_T / 64, DIM / 64, 3), 256, 0, stream>>>(
        image, text, w_text, w_image, image_bf, text_bf, imgT, textT,
        wt_bf, wi_bf, lT);

    gemm_proj2<<<dim3(N_T / 128, DIM / 64, 2), 256, 0, stream>>>(
        text_bf, wt_bf, b_text, t_bf, image_bf, wi_bf, b_image, i_bf);

    gemm_logits_exp<<<dim3(N_T / 128, N_I / 128), 256, 0, stream>>>(t_bf, i_bf, P, PT, lT, lI);

    gemm_attn2<<<dim3(N_T / 128, DIM / 128, 2), 512, 0, stream>>>(
        P, imgT, lT, scale_TI, out0, PT, textT, lI, scale_IT, out1);
}

// Round 10
// 266.113 us; speedup vs baseline: 2.0536x; 2.0536x over previous
//
#include <hip/hip_runtime.h>

// ---------------------------------------------------------------------------
// ImageTextModule: dual cross-attention between text and image feature sets.
//   t = text @ w_text^T + b_text ; i = image @ w_image^T + b_image  (bf16)
//   P  = exp((t @ i^T) / 32)  materialized ONCE in bf16, BOTH layouts (P, PT);
//        row/col exp-sums fused (wave-pair LDS pre-combine -> 1 atomic per
//        row/col per block).
//   out0 = (scale_TI / lT) * P  @ image ; out1 = (scale_IT / lI) * PT @ text
// attn: 512-thr, in-block split-K=2, 2x unroll, ASYMMETRIC LDS merge
//       (half-1 donates all + retires; half-0 finishes + stores). Round-9's
//       symmetric 2-sync merge forced both halves' 64 acc VGPRs live across
//       divergent barriers -> compiler spilled to scratch (WRITE_SIZE 2.2 GB,
//       4x slowdown). Asymmetric form measured 87.0 µs — do not "improve" it.
// proj: 128x64 tiles -> 1024 blocks = 4/CU (round-9: kept, mildly positive).
// K-loops: m97 structure — unpadded [rows][32] LDS, global_load_lds width-16,
// bf16 MFMA 16x16x32, fp32 accumulate.  Workspace: 96 MB + 32 KB.
// ---------------------------------------------------------------------------

typedef __bf16 bf16x8 __attribute__((ext_vector_type(8)));
typedef float f32x4 __attribute__((ext_vector_type(4)));

#define N_T 4096
#define N_I 4096
#define DIM 1024
#define TSS 136  // epilogue tile stride (bf16): 128 + 8 pad

__device__ __forceinline__ unsigned short f2bf(float f) {
    unsigned int u = __float_as_uint(f);
    u += 0x7fffu + ((u >> 16) & 1u);  // RNE
    return (unsigned short)(u >> 16);
}

// 16-byte async global->LDS DMA (no VGPR round-trip).
__device__ __forceinline__ void async_cp16(const unsigned short* g, unsigned short* l) {
    __builtin_amdgcn_global_load_lds(
        (const __attribute__((address_space(1))) unsigned int*)g,
        (__attribute__((address_space(3))) unsigned int*)l, 16, 0, 0);
}

// Stage 128x32 bf16 tile -> unpadded LDS [128][32] with 256 threads.
__device__ __forceinline__ void stage_async(const unsigned short* __restrict__ src,
                                            int ld, int row0, int k0,
                                            unsigned short* lds, int t) {
    int r = t >> 2, c = (t & 3) << 3;
    const unsigned short* g = src + (size_t)(row0 + r) * ld + k0 + c;
    async_cp16(g, lds + r * 32 + c);
    async_cp16(g + (size_t)64 * ld, lds + (64 + r) * 32 + c);
}

// Stage 64x32 bf16 tile -> unpadded LDS [64][32] with 256 threads (1 cp16 ea).
__device__ __forceinline__ void stage_async64(const unsigned short* __restrict__ src,
                                              int ld, int row0, int k0,
                                              unsigned short* lds, int t) {
    int r = t >> 2, c = (t & 3) << 3;
    async_cp16(src + (size_t)(row0 + r) * ld + k0 + c, lds + r * 32 + c);
}

// One BK=32 MFMA step, 4x4 frags (64x64 wave tile).
__device__ __forceinline__ void mfma_step(const unsigned short* As,
                                          const unsigned short* Bs, f32x4 acc[4][4],
                                          int wrow, int wcol, int lane16, int quad) {
    bf16x8 a[4], b[4];
#pragma unroll
    for (int i = 0; i < 4; ++i) {
        a[i] = *(const bf16x8*)&As[(wrow + i * 16 + lane16) * 32 + quad * 8];
        b[i] = *(const bf16x8*)&Bs[(wcol + i * 16 + lane16) * 32 + quad * 8];
    }
#pragma unroll
    for (int i = 0; i < 4; ++i)
#pragma unroll
        for (int j = 0; j < 4; ++j)
            acc[i][j] = __builtin_amdgcn_mfma_f32_16x16x32_bf16(a[i], b[j], acc[i][j], 0, 0, 0);
}

// One BK=32 MFMA step, 4x2 frags (64x32 wave tile) — proj's 128x64 tiling.
__device__ __forceinline__ void mfma_step42(const unsigned short* As,
                                            const unsigned short* Bs, f32x4 acc[4][2],
                                            int wrow, int wcol, int lane16, int quad) {
    bf16x8 a[4], b[2];
#pragma unroll
    for (int i = 0; i < 4; ++i)
        a[i] = *(const bf16x8*)&As[(wrow + i * 16 + lane16) * 32 + quad * 8];
#pragma unroll
    for (int j = 0; j < 2; ++j)
        b[j] = *(const bf16x8*)&Bs[(wcol + j * 16 + lane16) * 32 + quad * 8];
#pragma unroll
    for (int i = 0; i < 4; ++i)
#pragma unroll
        for (int j = 0; j < 2; ++j)
            acc[i][j] = __builtin_amdgcn_mfma_f32_16x16x32_bf16(a[i], b[j], acc[i][j], 0, 0, 0);
}

// Coalesced 128x128 bf16 tile store from LDS (stride TSS) to global.
__device__ __forceinline__ void tile_store(const unsigned short* sm,
                                           unsigned short* __restrict__ g, int ld,
                                           int row0, int col0, int tid) {
    int r = tid >> 1, h = (tid & 1) << 6;
    const unsigned short* src = sm + r * TSS + h;
    unsigned short* dst = g + (size_t)(row0 + r) * ld + col0 + h;
#pragma unroll
    for (int v = 0; v < 8; ++v)
        *(uint4*)(dst + v * 8) = *(const uint4*)(src + v * 8);
}

// ---- unified pre-pass ------------------------------------------------------
// z=0: image 64x64 tile -> image_bf + imgT      z=1: text -> text_bf + textT
// z=2: weights flat cvt (lin id over 1024 blocks); blocks 0-3 zero lT/lI.
__global__ void __launch_bounds__(256)
cvt_all(const float* __restrict__ im, const float* __restrict__ tx,
        const float* __restrict__ wt, const float* __restrict__ wi,
        unsigned short* __restrict__ imb, unsigned short* __restrict__ txb,
        unsigned short* __restrict__ imgT, unsigned short* __restrict__ textT,
        unsigned short* __restrict__ wtb, unsigned short* __restrict__ wib,
        float* __restrict__ lTI) {
    int t = threadIdx.x;
    if (blockIdx.z == 2) {
        int lin = blockIdx.y * 64 + blockIdx.x;  // 0..1023
        if (lin < 4) {
            *(f32x4*)&lTI[(lin * 256 + t) * 8] = (f32x4){0.f, 0.f, 0.f, 0.f};
            *(f32x4*)&lTI[(lin * 256 + t) * 8 + 4] = (f32x4){0.f, 0.f, 0.f, 0.f};
        }
        size_t i = (size_t)(lin * 256 + t) * 8;
        const float* s;
        unsigned short* d;
        size_t off;
        if (i < 1048576) { s = wt; d = wtb; off = i; }
        else             { s = wi; d = wib; off = i - 1048576; }
        float4 f0 = *(const float4*)(s + off);
        float4 f1 = *(const float4*)(s + off + 4);
        uint4 o;
        o.x = (unsigned int)f2bf(f0.x) | ((unsigned int)f2bf(f0.y) << 16);
        o.y = (unsigned int)f2bf(f0.z) | ((unsigned int)f2bf(f0.w) << 16);
        o.z = (unsigned int)f2bf(f1.x) | ((unsigned int)f2bf(f1.y) << 16);
        o.w = (unsigned int)f2bf(f1.z) | ((unsigned int)f2bf(f1.w) << 16);
        *(uint4*)(d + off) = o;
        return;
    }
    const float* in = blockIdx.z ? tx : im;
    unsigned short* nb = blockIdx.z ? txb : imb;
    unsigned short* tr = blockIdx.z ? textT : imgT;
    __shared__ float tile[64][65];
    int row0 = blockIdx.x * 64, col0 = blockIdx.y * 64;
    int r = t >> 2, c = (t & 3) << 4;  // 64 rows x 4 col-chunks of 16
    {
        const float* p = in + (size_t)(row0 + r) * DIM + col0 + c;
        float4 f0 = *(const float4*)(p);
        float4 f1 = *(const float4*)(p + 4);
        float4 f2 = *(const float4*)(p + 8);
        float4 f3 = *(const float4*)(p + 12);
        *(float4*)&tile[r][c] = f0;
        *(float4*)&tile[r][c + 4] = f1;
        *(float4*)&tile[r][c + 8] = f2;
        *(float4*)&tile[r][c + 12] = f3;
        uint4 o0, o1;
        o0.x = (unsigned int)f2bf(f0.x) | ((unsigned int)f2bf(f0.y) << 16);
        o0.y = (unsigned int)f2bf(f0.z) | ((unsigned int)f2bf(f0.w) << 16);
        o0.z = (unsigned int)f2bf(f1.x) | ((unsigned int)f2bf(f1.y) << 16);
        o0.w = (unsigned int)f2bf(f1.z) | ((unsigned int)f2bf(f1.w) << 16);
        o1.x = (unsigned int)f2bf(f2.x) | ((unsigned int)f2bf(f2.y) << 16);
        o1.y = (unsigned int)f2bf(f2.z) | ((unsigned int)f2bf(f2.w) << 16);
        o1.z = (unsigned int)f2bf(f3.x) | ((unsigned int)f2bf(f3.y) << 16);
        o1.w = (unsigned int)f2bf(f3.z) | ((unsigned int)f2bf(f3.w) << 16);
        unsigned short* q = nb + (size_t)(row0 + r) * DIM + col0 + c;
        *(uint4*)q = o0;
        *(uint4*)(q + 8) = o1;
    }
    __syncthreads();
    {
        unsigned short v[16];
#pragma unroll
        for (int u = 0; u < 16; ++u) v[u] = f2bf(tile[c + u][r]);
        unsigned short* q = tr + (size_t)(col0 + r) * N_T + row0 + c;
        *(uint4*)q = *(uint4*)&v[0];
        *(uint4*)(q + 8) = *(uint4*)&v[8];
    }
}

// ---- fused projections: 128x64 tiles, 1024 blocks = 4/CU, 32 waves/CU ------
// C_bf16[4096][1024] = A_bf16 @ W_bf16^T + bias.  z: text / image.
__global__ void __launch_bounds__(256, 4)
gemm_proj2(const unsigned short* __restrict__ Atx, const unsigned short* __restrict__ Wtx,
           const float* __restrict__ btx, unsigned short* __restrict__ Ctx,
           const unsigned short* __restrict__ Aim, const unsigned short* __restrict__ Wim,
           const float* __restrict__ bim, unsigned short* __restrict__ Cim) {
    __shared__ unsigned short As[2][128 * 32];  // 16 KB
    __shared__ unsigned short Bs[2][64 * 32];   // 8 KB
    int z = blockIdx.z;
    const unsigned short* A = z ? Aim : Atx;
    const unsigned short* W = z ? Wim : Wtx;
    const float* bias = z ? bim : btx;
    unsigned short* C = z ? Cim : Ctx;
    int tid = threadIdx.x;
    int m0 = blockIdx.x * 128, n0 = blockIdx.y * 64;
    int lane = tid & 63, wave = tid >> 6;
    int lane16 = lane & 15, quad = lane >> 4;
    int wrow = (wave >> 1) * 64, wcol = (wave & 1) * 32;
    f32x4 acc[4][2];
    {
        f32x4 zz = {0.f, 0.f, 0.f, 0.f};
        for (int i = 0; i < 4; ++i)
            for (int j = 0; j < 2; ++j) acc[i][j] = zz;
    }
    for (int k0 = 0; k0 < DIM; k0 += 64) {
        stage_async(A, DIM, m0, k0, As[0], tid);
        stage_async64(W, DIM, n0, k0, Bs[0], tid);
        stage_async(A, DIM, m0, k0 + 32, As[1], tid);
        stage_async64(W, DIM, n0, k0 + 32, Bs[1], tid);
        __syncthreads();
        mfma_step42(As[0], Bs[0], acc, wrow, wcol, lane16, quad);
        mfma_step42(As[1], Bs[1], acc, wrow, wcol, lane16, quad);
        __syncthreads();
    }
#pragma unroll
    for (int j = 0; j < 2; ++j) {
        int col = n0 + wcol + j * 16 + lane16;
        float bv = bias[col];
#pragma unroll
        for (int i = 0; i < 4; ++i) {
            int rowb = m0 + wrow + i * 16 + quad * 4;
#pragma unroll
            for (int r = 0; r < 4; ++r)
                C[(size_t)(rowb + r) * DIM + col] = f2bf(acc[i][j][r] + bv);
        }
    }
}

// ---- logits+exp: P/PT bf16 (both layouts) + fused row/col exp-sums ---------
// Wave-pair LDS pre-combine -> one atomic per row/col per block.
__global__ void __launch_bounds__(256, 4)
gemm_logits_exp(const unsigned short* __restrict__ Tb,
                const unsigned short* __restrict__ Ib,
                unsigned short* __restrict__ P, unsigned short* __restrict__ PT,
                float* __restrict__ lT, float* __restrict__ lI) {
    __shared__ unsigned short smem[128 * TSS];  // 34.8 KB: K-bufs + epilogue
    unsigned short* As0 = smem;
    unsigned short* Bs0 = smem + 4096;
    unsigned short* As1 = smem + 8192;
    unsigned short* Bs1 = smem + 12288;
    float* lred = (float*)(smem + 16384);  // 128 floats (free tail of smem)
    float* cred = lred + 128;              // 128 floats
    int tid = threadIdx.x;
    int m0 = blockIdx.x * 128, n0 = blockIdx.y * 128;
    int lane = tid & 63, wave = tid >> 6;
    int lane16 = lane & 15, quad = lane >> 4;
    int wrow = (wave >> 1) * 64, wcol = (wave & 1) * 64;
    f32x4 acc[4][4];
    {
        f32x4 z = {0.f, 0.f, 0.f, 0.f};
        for (int i = 0; i < 4; ++i)
            for (int j = 0; j < 4; ++j) acc[i][j] = z;
    }
    for (int k0 = 0; k0 < DIM; k0 += 64) {
        stage_async(Tb, DIM, m0, k0, As0, tid);
        stage_async(Ib, DIM, n0, k0, Bs0, tid);
        stage_async(Tb, DIM, m0, k0 + 32, As1, tid);
        stage_async(Ib, DIM, n0, k0 + 32, Bs1, tid);
        __syncthreads();
        mfma_step(As0, Bs0, acc, wrow, wcol, lane16, quad);
        mfma_step(As1, Bs1, acc, wrow, wcol, lane16, quad);
        __syncthreads();
    }
    // p = exp(logit/32) in place (fp32)
#pragma unroll
    for (int i = 0; i < 4; ++i)
#pragma unroll
        for (int j = 0; j < 4; ++j)
#pragma unroll
            for (int r = 0; r < 4; ++r)
                acc[i][j][r] = __expf(acc[i][j][r] * 0.03125f);
    // wave partials: rows (this wave's 64 cols) and cols (this wave's 64 rows)
    float rs[4][4];  // row partial, valid at lane16==0
#pragma unroll
    for (int i = 0; i < 4; ++i)
#pragma unroll
        for (int r = 0; r < 4; ++r) {
            float s = acc[i][0][r] + acc[i][1][r] + acc[i][2][r] + acc[i][3][r];
            s += __shfl_xor(s, 1); s += __shfl_xor(s, 2);
            s += __shfl_xor(s, 4); s += __shfl_xor(s, 8);
            rs[i][r] = s;
        }
    float cs[4];  // col partial, valid at quad==0
#pragma unroll
    for (int j = 0; j < 4; ++j) {
        float s = 0.f;
#pragma unroll
        for (int i = 0; i < 4; ++i)
#pragma unroll
            for (int r = 0; r < 4; ++r) s += acc[i][j][r];
        s += __shfl_xor(s, 16); s += __shfl_xor(s, 32);
        cs[j] = s;
    }
    // donors: waves 1,3 stash row partials; waves 2,3 stash col partials
    if (wave & 1) {
        if (lane16 == 0)
#pragma unroll
            for (int i = 0; i < 4; ++i)
#pragma unroll
                for (int r = 0; r < 4; ++r)
                    lred[wrow + i * 16 + quad * 4 + r] = rs[i][r];
    }
    if (wave >> 1) {
        if (quad == 0)
#pragma unroll
            for (int j = 0; j < 4; ++j)
                cred[wcol + j * 16 + lane16] = cs[j];
    }
    __syncthreads();
    // combiners: waves 0,2 finish rows; waves 0,1 finish cols
    if (!(wave & 1) && lane16 == 0) {
#pragma unroll
        for (int i = 0; i < 4; ++i)
#pragma unroll
            for (int r = 0; r < 4; ++r) {
                int row = wrow + i * 16 + quad * 4 + r;
                atomicAdd(&lT[m0 + row], rs[i][r] + lred[row]);
            }
    }
    if (!(wave >> 1) && quad == 0) {
#pragma unroll
        for (int j = 0; j < 4; ++j) {
            int col = wcol + j * 16 + lane16;
            atomicAdd(&lI[n0 + col], cs[j] + cred[col]);
        }
    }
    // pass 1: normal-layout tile -> P (coalesced b128 stores)
    __syncthreads();
#pragma unroll
    for (int i = 0; i < 4; ++i)
#pragma unroll
        for (int j = 0; j < 4; ++j)
#pragma unroll
            for (int r = 0; r < 4; ++r)
                smem[(wrow + i * 16 + quad * 4 + r) * TSS + wcol + j * 16 + lane16] =
                    f2bf(acc[i][j][r]);
    __syncthreads();
    tile_store(smem, P, N_I, m0, n0, tid);
    // pass 2: transposed tile -> PT (b64 LDS writes, coalesced b128 stores)
    __syncthreads();
#pragma unroll
    for (int i = 0; i < 4; ++i)
#pragma unroll
        for (int j = 0; j < 4; ++j) {
            unsigned int lo = (unsigned int)f2bf(acc[i][j][0]) |
                              ((unsigned int)f2bf(acc[i][j][1]) << 16);
            unsigned int hi = (unsigned int)f2bf(acc[i][j][2]) |
                              ((unsigned int)f2bf(acc[i][j][3]) << 16);
            uint2 v; v.x = lo; v.y = hi;
            *(uint2*)&smem[(wcol + j * 16 + lane16) * TSS + wrow + i * 16 + quad * 4] = v;
        }
    __syncthreads();
    tile_store(smem, PT, N_T, n0, m0, tid);
}

// ---- fused attention GEMMs: 512 thr, split-K=2, 2x unroll ------------------
// z: which problem. out[m][d] = (scale/l[m]) * sum_k A[m][k] * Bt[d][k].
// ASYMMETRIC merge (round-8 measured 87.0 µs): half-1 donates all acc and
// retires; half-0 finishes and stores. Keeps half-1's acc dead after donation
// -> no spill (round-9's symmetric merge spilled: WRITE_SIZE 2.2 GB).
__global__ void __launch_bounds__(512, 4)
gemm_attn2(const unsigned short* __restrict__ P, const unsigned short* __restrict__ imgT,
           const float* __restrict__ lT, const float* __restrict__ sTI,
           float* __restrict__ out0,
           const unsigned short* __restrict__ PT, const unsigned short* __restrict__ textT,
           const float* __restrict__ lI, const float* __restrict__ sIT,
           float* __restrict__ out1) {
    __shared__ unsigned short As[2][2][128 * 32];  // [half][unroll] 32 KB
    __shared__ unsigned short Bs[2][2][128 * 32];  // 32 KB
    int which = blockIdx.z;
    const unsigned short* A = which ? PT : P;
    const unsigned short* Bt = which ? textT : imgT;
    const float* l = which ? lI : lT;
    const float* sp = which ? sIT : sTI;
    float* out = which ? out1 : out0;

    int tid = threadIdx.x;            // 0..511
    int half = tid >> 8;              // K-half (wave-uniform)
    int t = tid & 255;                // index within half-group
    int m0 = blockIdx.x * 128, n0 = blockIdx.y * 128;
    int lane = tid & 63;
    int wv = (tid >> 6) & 3;          // wave within half-group
    int lane16 = lane & 15, quad = lane >> 4;
    int wrow = (wv >> 1) * 64, wcol = (wv & 1) * 64;
    f32x4 acc[4][4];
    {
        f32x4 z = {0.f, 0.f, 0.f, 0.f};
        for (int i = 0; i < 4; ++i)
            for (int j = 0; j < 4; ++j) acc[i][j] = z;
    }

    int kbeg = half * 2048;
    for (int k0 = kbeg; k0 < kbeg + 2048; k0 += 64) {  // 32 lockstep iterations
        stage_async(A, 4096, m0, k0, As[half][0], t);
        stage_async(Bt, 4096, n0, k0, Bs[half][0], t);
        stage_async(A, 4096, m0, k0 + 32, As[half][1], t);
        stage_async(Bt, 4096, n0, k0 + 32, Bs[half][1], t);
        __syncthreads();
        mfma_step(As[half][0], Bs[half][0], acc, wrow, wcol, lane16, quad);
        mfma_step(As[half][1], Bs[half][1], acc, wrow, wcol, lane16, quad);
        __syncthreads();
    }

    // Merge the two K-halves through LDS, 4 chunks of 16 KB (reuse As).
    // Layout stride 16 floats/lane -> 2-way bank aliasing only (free, m136).
    float* red = (float*)As;
#pragma unroll
    for (int i = 0; i < 4; ++i) {
        __syncthreads();
        if (half) {
#pragma unroll
            for (int j = 0; j < 4; ++j)
                *(f32x4*)&red[wv * 1024 + lane * 16 + j * 4] = acc[i][j];
        }
        __syncthreads();
        if (!half) {
#pragma unroll
            for (int j = 0; j < 4; ++j)
                acc[i][j] += *(const f32x4*)&red[wv * 1024 + lane * 16 + j * 4];
        }
    }
    if (half) return;  // no barriers below

    float sc = sp[0];
#pragma unroll
    for (int i = 0; i < 4; ++i) {
        int rowb = m0 + wrow + i * 16 + quad * 4;
        float fac[4];
#pragma unroll
        for (int r = 0; r < 4; ++r) fac[r] = sc / l[rowb + r];
#pragma unroll
        for (int j = 0; j < 4; ++j) {
            int col = n0 + wcol + j * 16 + lane16;
#pragma unroll
            for (int r = 0; r < 4; ++r)
                out[(size_t)(rowb + r) * DIM + col] = acc[i][j][r] * fac[r];
        }
    }
}

extern "C" void kernel_launch(void* const* d_in, const int* in_sizes, int n_in,
                              void* d_out, int out_size, void* d_ws, size_t ws_size,
                              hipStream_t stream) {
    const float* text = (const float*)d_in[0];
    const float* image = (const float*)d_in[1];
    const float* w_text = (const float*)d_in[2];
    const float* b_text = (const float*)d_in[3];
    const float* w_image = (const float*)d_in[4];
    const float* b_image = (const float*)d_in[5];
    const float* scale_TI = (const float*)d_in[6];
    const float* scale_IT = (const float*)d_in[7];
    float* out0 = (float*)d_out;
    float* out1 = out0 + (size_t)N_T * DIM;

    // Workspace layout (96 MB + 32 KB). cvt buffers [0,20MB) die after proj2;
    // gemm_logits_exp then writes P over [0,32MB) — lifetimes disjoint.
    char* ws = (char*)d_ws;
    unsigned short* text_bf = (unsigned short*)(ws);                 // 8 MB  (dies after proj)
    unsigned short* image_bf = (unsigned short*)(ws + (8ull << 20)); // 8 MB  (dies after proj)
    unsigned short* wt_bf = (unsigned short*)(ws + (16ull << 20));   // 2 MB  (dies after proj)
    unsigned short* wi_bf = (unsigned short*)(ws + (18ull << 20));   // 2 MB  (dies after proj)
    unsigned short* P = (unsigned short*)(ws);                       // 32 MB (logits -> attn)
    unsigned short* imgT = (unsigned short*)(ws + (32ull << 20));    // 8 MB
    unsigned short* textT = (unsigned short*)(ws + (40ull << 20));   // 8 MB
    unsigned short* t_bf = (unsigned short*)(ws + (48ull << 20));    // 8 MB
    unsigned short* i_bf = (unsigned short*)(ws + (56ull << 20));    // 8 MB
    unsigned short* PT = (unsigned short*)(ws + (64ull << 20));      // 32 MB
    float* lT = (float*)(ws + (96ull << 20));                        // 16 KB
    float* lI = (float*)(ws + (96ull << 20) + 16384);                // 16 KB

    // z=0/1: feature 64x64 cvt+transpose tiles; z=2: weights cvt + lT/lI zero.
    cvt_all<<<dim3(N_T / 64, DIM / 64, 3), 256, 0, stream>>>(
        image, text, w_text, w_image, image_bf, text_bf, imgT, textT,
        wt_bf, wi_bf, lT);

    gemm_proj2<<<dim3(N_T / 128, DIM / 64, 2), 256, 0, stream>>>(
        text_bf, wt_bf, b_text, t_bf, image_bf, wi_bf, b_image, i_bf);

    gemm_logits_exp<<<dim3(N_T / 128, N_I / 128), 256, 0, stream>>>(t_bf, i_bf, P, PT, lT, lI);

    gemm_attn2<<<dim3(N_T / 128, DIM / 128, 2), 512, 0, stream>>>(
        P, imgT, lT, scale_TI, out0, PT, textT, lI, scale_IT, out1);
}